// Round 2
// baseline (342.904 us; speedup 1.0000x reference)
//
#include <hip/hip_runtime.h>
#include <stdint.h>

typedef unsigned short u16;
typedef unsigned int u32;

using bf16x8 = __attribute__((ext_vector_type(8))) short;
using f32x4  = __attribute__((ext_vector_type(4))) float;

#define DEVINL __device__ __forceinline__

DEVINL float b2f(u16 u) { return __builtin_bit_cast(float, (u32)u << 16); }
DEVINL u16 f2b(float f) {
  u32 u = __builtin_bit_cast(u32, f);
  u += 0x7FFFu + ((u >> 16) & 1u);   // round-to-nearest-even
  return (u16)(u >> 16);
}

// ---------------------------------------------------------------- convert+transpose
// src: batch z of R x C f32 (row-major) -> dst: C x R bf16
__global__ __launch_bounds__(256) void transpose_f32_bf16(
    const float* __restrict__ src, u16* __restrict__ dst, int R, int C)
{
  __shared__ u16 tile[32][33];
  const size_t mstride = (size_t)R * C;
  const float* s = src + (size_t)blockIdx.z * mstride;
  u16* d = dst + (size_t)blockIdx.z * mstride;
  int r0 = blockIdx.x * 32, c0 = blockIdx.y * 32;
  int tx = threadIdx.x & 31, ty = threadIdx.x >> 5;  // ty: 0..7
#pragma unroll
  for (int i = 0; i < 32; i += 8)
    tile[ty + i][tx] = f2b(s[(size_t)(r0 + ty + i) * C + (c0 + tx)]);
  __syncthreads();
#pragma unroll
  for (int i = 0; i < 32; i += 8)
    d[(size_t)(c0 + ty + i) * R + (r0 + tx)] = tile[tx][ty + i];
}

// ---------------------------------------------------------------- layernorm
// f32 input (obs, D=256), bf16 output. one wave per row.
__global__ __launch_bounds__(256) void ln_f32_256(
    const float* __restrict__ X, const float* __restrict__ sc,
    const float* __restrict__ bi, u16* __restrict__ Y, int nrows)
{
  constexpr int D = 256, PER = 4;
  int lane = threadIdx.x & 63;
  int row = blockIdx.x * 4 + (threadIdx.x >> 6);
  if (row >= nrows) return;
  const float* xr = X + (size_t)row * D + lane * PER;
  float x[PER] __attribute__((aligned(16)));
  *(float4*)x = *(const float4*)xr;
  float s = 0.f, s2 = 0.f;
#pragma unroll
  for (int p = 0; p < PER; ++p) { s += x[p]; s2 += x[p] * x[p]; }
#pragma unroll
  for (int o = 32; o > 0; o >>= 1) { s += __shfl_xor(s, o, 64); s2 += __shfl_xor(s2, o, 64); }
  float m = s * (1.f / D);
  float v = s2 * (1.f / D) - m * m;
  float inv = rsqrtf(v + 1e-5f);
  u16 yu[PER] __attribute__((aligned(8)));
#pragma unroll
  for (int p = 0; p < PER; ++p)
    yu[p] = f2b((x[p] - m) * inv * sc[lane * PER + p] + bi[lane * PER + p]);
  *(uint2*)(Y + (size_t)row * D + lane * PER) = *(uint2*)yu;
}

// bf16 input (hidden, D=512), bf16 output. one wave per row.
__global__ __launch_bounds__(256) void ln_bf16_512(
    const u16* __restrict__ X, const float* __restrict__ sc,
    const float* __restrict__ bi, u16* __restrict__ Y, int nrows)
{
  constexpr int D = 512, PER = 8;
  int lane = threadIdx.x & 63;
  int row = blockIdx.x * 4 + (threadIdx.x >> 6);
  if (row >= nrows) return;
  const u16* xr = X + (size_t)row * D + lane * PER;
  u16 xu[PER] __attribute__((aligned(16)));
  *(uint4*)xu = *(const uint4*)xr;
  float x[PER]; float s = 0.f, s2 = 0.f;
#pragma unroll
  for (int p = 0; p < PER; ++p) { x[p] = b2f(xu[p]); s += x[p]; s2 += x[p] * x[p]; }
#pragma unroll
  for (int o = 32; o > 0; o >>= 1) { s += __shfl_xor(s, o, 64); s2 += __shfl_xor(s2, o, 64); }
  float m = s * (1.f / D);
  float v = s2 * (1.f / D) - m * m;
  float inv = rsqrtf(v + 1e-5f);
  u16 yu[PER] __attribute__((aligned(16)));
#pragma unroll
  for (int p = 0; p < PER; ++p)
    yu[p] = f2b((x[p] - m) * inv * sc[lane * PER + p] + bi[lane * PER + p]);
  *(uint4*)(Y + (size_t)row * D + lane * PER) = *(uint4*)yu;
}

// ---------------------------------------------------------------- role bucketing
#define NROLE 6
__global__ __launch_bounds__(256) void role_count(
    const int* __restrict__ rid, int* __restrict__ blkCnt)
{
  __shared__ int h[NROLE];
  if (threadIdx.x < NROLE) h[threadIdx.x] = 0;
  __syncthreads();
  int i = blockIdx.x * 256 + threadIdx.x;
  atomicAdd(&h[rid[i]], 1);
  __syncthreads();
  if (threadIdx.x < NROLE) blkCnt[blockIdx.x * NROLE + threadIdx.x] = h[threadIdx.x];
}

__global__ __launch_bounds__(256) void role_scan(
    const int* __restrict__ blkCnt, int* __restrict__ blkBase,
    int* __restrict__ baseArr, int* __restrict__ cntArr)
{
  __shared__ int c[128 * NROLE];
  __shared__ int bb[128 * NROLE];
  __shared__ int sbase[NROLE], scnt[NROLE];
  for (int i = threadIdx.x; i < 128 * NROLE; i += 256) c[i] = blkCnt[i];
  __syncthreads();
  if (threadIdx.x < NROLE) {
    int k = threadIdx.x, run = 0;
    for (int b = 0; b < 128; ++b) { bb[b * NROLE + k] = run; run += c[b * NROLE + k]; }
    scnt[k] = run;
  }
  __syncthreads();
  if (threadIdx.x == 0) {
    int r = 0;
    for (int k = 0; k < NROLE; ++k) { sbase[k] = r; r += scnt[k]; }
  }
  __syncthreads();
  if (threadIdx.x < NROLE) { baseArr[threadIdx.x] = sbase[threadIdx.x]; cntArr[threadIdx.x] = scnt[threadIdx.x]; }
  for (int i = threadIdx.x; i < 128 * NROLE; i += 256)
    blkBase[i] = bb[i] + sbase[i % NROLE];
}

__global__ __launch_bounds__(256) void role_fill(
    const int* __restrict__ rid, const int* __restrict__ blkBase, int* __restrict__ bucket)
{
  __shared__ int h[NROLE];
  if (threadIdx.x < NROLE) h[threadIdx.x] = 0;
  __syncthreads();
  int i = blockIdx.x * 256 + threadIdx.x;
  int k = rid[i];
  int pos = atomicAdd(&h[k], 1);
  bucket[blkBase[blockIdx.x * NROLE + k] + pos] = i;
}

// ---------------------------------------------------------------- MFMA GEMM
// C[M x N] = relu(A[M x K] @ Bt[N x K]^T + bias), bf16 A/Bt/C, f32 bias+accum.
// MODE: 0 dense, 1 gather-A(contig C), 2 contig-A(scatter C, += into C)
enum { GM_DENSE = 0, GM_GATHER = 1, GM_SCATTER = 2 };

template <int BN, int NF, int MODE>
__global__ __launch_bounds__(256) void gemm_bf16(
    const u16* __restrict__ A, const u16* __restrict__ Bt,
    const float* __restrict__ bias, u16* __restrict__ C,
    const int* __restrict__ bucket, const int* __restrict__ baseArr,
    const int* __restrict__ cntArr, int M, int N, int K, int ldc)
{
  constexpr int BM = 128, BK = 64;
  __shared__ __align__(16) u16 As[BM * BK];
  __shared__ __align__(16) u16 Bs[BN * BK];
  const int tid = threadIdx.x;
  const int role = blockIdx.z;
  const int rowBase = blockIdx.x * BM;
  int limit;
  if constexpr (MODE == GM_DENSE) limit = M; else limit = cntArr[role];
  if (rowBase >= limit) return;
  int roleBase = 0;
  if constexpr (MODE != GM_DENSE) roleBase = baseArr[role];
  const u16* BtK = Bt + (size_t)role * N * K + (size_t)blockIdx.y * BN * K;
  const float* biasK = bias + (size_t)role * N + (size_t)blockIdx.y * BN;

  const int lane = tid & 63;
  const int wave = tid >> 6;

  // staging source pointers (16B per thread per round)
  const u16* aSrc[4];
#pragma unroll
  for (int r = 0; r < 4; ++r) {
    int off = r * 2048 + tid * 8;      // elem offset in 128x64 tile
    int arow = off >> 6;
    int acol = off & 63;
    int i = rowBase + arow;
    if (i >= limit) i = rowBase;       // valid clamp (rowBase < limit)
    int grow;
    if constexpr (MODE == GM_DENSE)       grow = i;
    else if constexpr (MODE == GM_GATHER) grow = bucket[roleBase + i];
    else                                  grow = roleBase + i;
    aSrc[r] = A + (size_t)grow * K + acol;
  }
  constexpr int BROUNDS = (BN * BK) / 2048;
  const u16* bSrc[BROUNDS];
#pragma unroll
  for (int r = 0; r < BROUNDS; ++r) {
    int off = r * 2048 + tid * 8;
    bSrc[r] = BtK + (size_t)(off >> 6) * K + (off & 63);
  }

  f32x4 acc[4][NF] = {};

  const int wm = (wave >> 1) * 64;
  const int wn = (wave & 1) * (NF * 16);
  const int quad = lane >> 4;
  const int lm = lane & 15;

  for (int k0 = 0; k0 < K; k0 += BK) {
#pragma unroll
    for (int r = 0; r < 4; ++r)
      __builtin_amdgcn_global_load_lds(
          (const __attribute__((address_space(1))) void*)(uintptr_t)(aSrc[r] + k0),
          (__attribute__((address_space(3))) void*)(&As[r * 2048 + wave * 512]),
          16, 0, 0);
#pragma unroll
    for (int r = 0; r < BROUNDS; ++r)
      __builtin_amdgcn_global_load_lds(
          (const __attribute__((address_space(1))) void*)(uintptr_t)(bSrc[r] + k0),
          (__attribute__((address_space(3))) void*)(&Bs[r * 2048 + wave * 512]),
          16, 0, 0);
    __syncthreads();
#pragma unroll
    for (int kk = 0; kk < BK; kk += 32) {
      bf16x8 af[4], bfr[NF];
#pragma unroll
      for (int i2 = 0; i2 < 4; ++i2)
        af[i2] = *(const bf16x8*)&As[(wm + i2 * 16 + lm) * BK + kk + quad * 8];
#pragma unroll
      for (int j = 0; j < NF; ++j)
        bfr[j] = *(const bf16x8*)&Bs[(wn + j * 16 + lm) * BK + kk + quad * 8];
#pragma unroll
      for (int i2 = 0; i2 < 4; ++i2)
#pragma unroll
        for (int j = 0; j < NF; ++j)
          acc[i2][j] = __builtin_amdgcn_mfma_f32_16x16x32_bf16(af[i2], bfr[j], acc[i2][j], 0, 0, 0);
    }
    __syncthreads();
  }

  // epilogue: C/D layout row=(lane>>4)*4+reg, col=lane&15
#pragma unroll
  for (int i2 = 0; i2 < 4; ++i2) {
#pragma unroll
    for (int r2 = 0; r2 < 4; ++r2) {
      int lrow = wm + i2 * 16 + quad * 4 + r2;
      int i = rowBase + lrow;
      if (i >= limit) continue;
      size_t crow;
      if constexpr (MODE == GM_DENSE)       crow = (size_t)i;
      else if constexpr (MODE == GM_GATHER) crow = (size_t)(roleBase + i);
      else                                  crow = (size_t)bucket[roleBase + i];
#pragma unroll
      for (int j = 0; j < NF; ++j) {
        int lcol = wn + j * 16 + lm;
        float v = fmaxf(acc[i2][j][r2] + biasK[lcol], 0.f);
        size_t cidx = crow * (size_t)ldc + (size_t)blockIdx.y * BN + lcol;
        if constexpr (MODE == GM_SCATTER) v += b2f(C[cidx]);
        C[cidx] = f2b(v);
      }
    }
  }
}

// ---------------------------------------------------------------- head tail
// per bucket-position p: h1 = relu(h0 @ Wh1[k] + bh1), logits = h1 @ Wh2[k] + bh2, mask
__global__ __launch_bounds__(256) void head_tail(
    const u16* __restrict__ h0buf, const int* __restrict__ bucket,
    const int* __restrict__ baseArr,
    const float* __restrict__ Wh1, const float* __restrict__ bh1,
    const float* __restrict__ Wh2, const float* __restrict__ bh2,
    const float* __restrict__ avail, float* __restrict__ outLogits)
{
  int lane = threadIdx.x & 63;
  int p = blockIdx.x * 4 + (threadIdx.x >> 6);
  int row = bucket[p];
  int k = 0;
#pragma unroll
  for (int j = 1; j < NROLE; ++j) k += (p >= baseArr[j]);
  float h0 = b2f(h0buf[(size_t)p * 64 + lane]);
  int n = lane & 31, half = lane >> 5;
  const float* W1k = Wh1 + k * 64 * 32;
  float a1 = 0.f;
#pragma unroll
  for (int jj = 0; jj < 32; ++jj) {
    int j = half * 32 + jj;
    float hj = __shfl(h0, j, 64);
    a1 += hj * W1k[j * 32 + n];
  }
  a1 += __shfl_xor(a1, 32, 64);
  float h1 = fmaxf(a1 + bh1[k * 32 + n], 0.f);
  const float* W2k = Wh2 + k * 32 * 32;
  float a2 = 0.f;
#pragma unroll
  for (int nn = 0; nn < 32; ++nn) {
    float hn = __shfl(h1, nn, 64);   // lane nn holds h1[nn]
    a2 += hn * W2k[nn * 32 + n];
  }
  float logit = a2 + bh2[k * 32 + n];
  float av = avail[(size_t)row * 32 + n];
  if (av <= 0.5f) logit = -1e10f;
  if (half == 0) outLogits[(size_t)row * 32 + n] = logit;
}

// ---------------------------------------------------------------- launcher
extern "C" void kernel_launch(void* const* d_in, const int* in_sizes, int n_in,
                              void* d_out, int out_size, void* d_ws, size_t ws_size,
                              hipStream_t stream)
{
  const float* rnn  = (const float*)d_in[0];
  const float* obs  = (const float*)d_in[1];
  const float* avail= (const float*)d_in[3];
  const int*   rid  = (const int*)d_in[4];
  const float* fn_s = (const float*)d_in[5];
  const float* fn_b = (const float*)d_in[6];
  const float* W0   = (const float*)d_in[7];
  const float* b0   = (const float*)d_in[8];
  const float* ln0s = (const float*)d_in[9];
  const float* ln0b = (const float*)d_in[10];
  const float* W1   = (const float*)d_in[11];
  const float* b1   = (const float*)d_in[12];
  const float* ln1s = (const float*)d_in[13];
  const float* ln1b = (const float*)d_in[14];
  const float* Wr0  = (const float*)d_in[15];
  const float* br0  = (const float*)d_in[16];
  const float* Wr1  = (const float*)d_in[17];
  const float* br1  = (const float*)d_in[18];
  const float* Wh0  = (const float*)d_in[19];
  const float* bh0  = (const float*)d_in[20];
  const float* Wh1  = (const float*)d_in[21];
  const float* bh1  = (const float*)d_in[22];
  const float* Wh2  = (const float*)d_in[23];
  const float* bh2  = (const float*)d_in[24];

  const int ROWS = 32768;           // T*B

  char* w = (char*)d_ws;
  auto carve = [&](size_t bytes) { char* p = w; w += (bytes + 255) & ~(size_t)255; return p; };
  u16* obs_n  = (u16*)carve((size_t)ROWS * 256 * 2);
  u16* bufA   = (u16*)carve((size_t)ROWS * 512 * 2);
  u16* bufB   = (u16*)carve((size_t)ROWS * 512 * 2);
  u16* r_buf  = (u16*)carve((size_t)ROWS * 128 * 2);
  u16* h0buf  = (u16*)carve((size_t)ROWS * 64 * 2);
  u16* W0t    = (u16*)carve((size_t)512 * 256 * 2);
  u16* W1t    = (u16*)carve((size_t)512 * 512 * 2);
  u16* Wr0t   = (u16*)carve((size_t)6 * 128 * 256 * 2);
  u16* Wr1t   = (u16*)carve((size_t)6 * 512 * 128 * 2);
  u16* Wh0t   = (u16*)carve((size_t)6 * 64 * 512 * 2);
  int* bucket = (int*)carve((size_t)ROWS * 4);
  int* blkCnt = (int*)carve((size_t)128 * NROLE * 4);
  int* blkBase= (int*)carve((size_t)128 * NROLE * 4);
  int* baseArr= (int*)carve(256);
  int* cntArr = (int*)carve(256);

  float* outLogits = (float*)d_out + (size_t)1024 * 512;   // after rnn passthrough

  // rnn_states passthrough (f32)
  hipMemcpyAsync(d_out, rnn, (size_t)1024 * 512 * 4, hipMemcpyDeviceToDevice, stream);

  // weight convert+transpose (K x N f32 -> N x K bf16)
  transpose_f32_bf16<<<dim3(8, 16, 1), 256, 0, stream>>>(W0, W0t, 256, 512);
  transpose_f32_bf16<<<dim3(16, 16, 1), 256, 0, stream>>>(W1, W1t, 512, 512);
  transpose_f32_bf16<<<dim3(8, 4, 6), 256, 0, stream>>>(Wr0, Wr0t, 256, 128);
  transpose_f32_bf16<<<dim3(4, 16, 6), 256, 0, stream>>>(Wr1, Wr1t, 128, 512);
  transpose_f32_bf16<<<dim3(16, 2, 6), 256, 0, stream>>>(Wh0, Wh0t, 512, 64);

  // feature norm (f32 obs -> bf16 obs_n)
  ln_f32_256<<<8192, 256, 0, stream>>>(obs, fn_s, fn_b, obs_n, ROWS);

  // role bucketing
  role_count<<<128, 256, 0, stream>>>(rid, blkCnt);
  role_scan<<<1, 256, 0, stream>>>(blkCnt, blkBase, baseArr, cntArr);
  role_fill<<<128, 256, 0, stream>>>(rid, blkBase, bucket);

  // base MLP
  gemm_bf16<128, 4, GM_DENSE><<<dim3(256, 4, 1), 256, 0, stream>>>(
      obs_n, W0t, b0, bufA, nullptr, nullptr, nullptr, ROWS, 512, 256, 512);
  ln_bf16_512<<<8192, 256, 0, stream>>>(bufA, ln0s, ln0b, bufB, ROWS);
  gemm_bf16<128, 4, GM_DENSE><<<dim3(256, 4, 1), 256, 0, stream>>>(
      bufB, W1t, b1, bufA, nullptr, nullptr, nullptr, ROWS, 512, 512, 512);
  ln_bf16_512<<<8192, 256, 0, stream>>>(bufA, ln1s, ln1b, bufB, ROWS);

  // role routes: obs_n -> 128 -> 512, added into e (bufB)
  gemm_bf16<128, 4, GM_GATHER><<<dim3(256, 1, 6), 256, 0, stream>>>(
      obs_n, Wr0t, br0, r_buf, bucket, baseArr, cntArr, ROWS, 128, 256, 128);
  gemm_bf16<128, 4, GM_SCATTER><<<dim3(256, 4, 6), 256, 0, stream>>>(
      r_buf, Wr1t, br1, bufB, bucket, baseArr, cntArr, ROWS, 512, 128, 512);

  // head first layer: e -> 64 (gathered rows, contiguous h0buf)
  gemm_bf16<64, 2, GM_GATHER><<<dim3(256, 1, 6), 256, 0, stream>>>(
      bufB, Wh0t, bh0, h0buf, bucket, baseArr, cntArr, ROWS, 64, 512, 64);

  // head tail: 64 -> 32 -> 32 + mask (f32 out)
  head_tail<<<8192, 256, 0, stream>>>(h0buf, bucket, baseArr, Wh1, bh1, Wh2, bh2, avail, outLogits);
}

// Round 3
// 302.343 us; speedup vs baseline: 1.1342x; 1.1342x over previous
//
#include <hip/hip_runtime.h>
#include <stdint.h>

typedef unsigned short u16;
typedef unsigned int u32;

using bf16x8 = __attribute__((ext_vector_type(8))) short;
using f32x4  = __attribute__((ext_vector_type(4))) float;

#define DEVINL __device__ __forceinline__

DEVINL float b2f(u16 u) { return __builtin_bit_cast(float, (u32)u << 16); }
DEVINL u16 f2b(float f) {
  u32 u = __builtin_bit_cast(u32, f);
  u += 0x7FFFu + ((u >> 16) & 1u);   // round-to-nearest-even
  return (u16)(u >> 16);
}

// ---------------------------------------------------------------- fused convert+transpose
// all 5 weight tensors, one launch. src R x C f32 (batch z) -> dst C x R bf16
DEVINL void tp_tile(const float* __restrict__ s, u16* __restrict__ d,
                    int R, int C, int bx, int by, int z)
{
  __shared__ u16 tile[32][33];
  const size_t mstride = (size_t)R * C;
  s += (size_t)z * mstride;
  d += (size_t)z * mstride;
  int r0 = bx * 32, c0 = by * 32;
  int tx = threadIdx.x & 31, ty = threadIdx.x >> 5;  // ty: 0..7
#pragma unroll
  for (int i = 0; i < 32; i += 8)
    tile[ty + i][tx] = f2b(s[(size_t)(r0 + ty + i) * C + (c0 + tx)]);
  __syncthreads();
#pragma unroll
  for (int i = 0; i < 32; i += 8)
    d[(size_t)(c0 + ty + i) * R + (r0 + tx)] = tile[tx][ty + i];
}

__global__ __launch_bounds__(256) void transpose_all(
    const float* W0, const float* W1, const float* Wr0, const float* Wr1, const float* Wh0,
    u16* W0t, u16* W1t, u16* Wr0t, u16* Wr1t, u16* Wh0t)
{
  int b = blockIdx.x;
  if (b < 128)      {            tp_tile(W0, W0t, 256, 512, b % 8,  b / 8, 0); }
  else if (b < 384) { b -= 128;  tp_tile(W1, W1t, 512, 512, b % 16, b / 16, 0); }
  else if (b < 576) { b -= 384;  int t = b / 8;  tp_tile(Wr0, Wr0t, 256, 128, b % 8,  t % 4,  t / 4); }
  else if (b < 960) { b -= 576;  int t = b / 4;  tp_tile(Wr1, Wr1t, 128, 512, b % 4,  t % 16, t / 16); }
  else              { b -= 960;  int t = b / 16; tp_tile(Wh0, Wh0t, 512, 64,  b % 16, t % 2,  t / 2); }
}

// ---------------------------------------------------------------- layernorm
__global__ __launch_bounds__(256) void ln_f32_256(
    const float* __restrict__ X, const float* __restrict__ sc,
    const float* __restrict__ bi, u16* __restrict__ Y, int nrows)
{
  constexpr int D = 256, PER = 4;
  int lane = threadIdx.x & 63;
  int row = blockIdx.x * 4 + (threadIdx.x >> 6);
  if (row >= nrows) return;
  const float* xr = X + (size_t)row * D + lane * PER;
  float x[PER] __attribute__((aligned(16)));
  *(float4*)x = *(const float4*)xr;
  float s = 0.f, s2 = 0.f;
#pragma unroll
  for (int p = 0; p < PER; ++p) { s += x[p]; s2 += x[p] * x[p]; }
#pragma unroll
  for (int o = 32; o > 0; o >>= 1) { s += __shfl_xor(s, o, 64); s2 += __shfl_xor(s2, o, 64); }
  float m = s * (1.f / D);
  float v = s2 * (1.f / D) - m * m;
  float inv = rsqrtf(v + 1e-5f);
  u16 yu[PER] __attribute__((aligned(8)));
#pragma unroll
  for (int p = 0; p < PER; ++p)
    yu[p] = f2b((x[p] - m) * inv * sc[lane * PER + p] + bi[lane * PER + p]);
  *(uint2*)(Y + (size_t)row * D + lane * PER) = *(uint2*)yu;
}

__global__ __launch_bounds__(256) void ln_bf16_512(
    const u16* __restrict__ X, const float* __restrict__ sc,
    const float* __restrict__ bi, u16* __restrict__ Y, int nrows)
{
  constexpr int D = 512, PER = 8;
  int lane = threadIdx.x & 63;
  int row = blockIdx.x * 4 + (threadIdx.x >> 6);
  if (row >= nrows) return;
  const u16* xr = X + (size_t)row * D + lane * PER;
  u16 xu[PER] __attribute__((aligned(16)));
  *(uint4*)xu = *(const uint4*)xr;
  float x[PER]; float s = 0.f, s2 = 0.f;
#pragma unroll
  for (int p = 0; p < PER; ++p) { x[p] = b2f(xu[p]); s += x[p]; s2 += x[p] * x[p]; }
#pragma unroll
  for (int o = 32; o > 0; o >>= 1) { s += __shfl_xor(s, o, 64); s2 += __shfl_xor(s2, o, 64); }
  float m = s * (1.f / D);
  float v = s2 * (1.f / D) - m * m;
  float inv = rsqrtf(v + 1e-5f);
  u16 yu[PER] __attribute__((aligned(16)));
#pragma unroll
  for (int p = 0; p < PER; ++p)
    yu[p] = f2b((x[p] - m) * inv * sc[lane * PER + p] + bi[lane * PER + p]);
  *(uint4*)(Y + (size_t)row * D + lane * PER) = *(uint4*)yu;
}

// ---------------------------------------------------------------- role bucketing
#define NROLE 6
__global__ __launch_bounds__(256) void role_count(
    const int* __restrict__ rid, int* __restrict__ blkCnt)
{
  __shared__ int h[NROLE];
  if (threadIdx.x < NROLE) h[threadIdx.x] = 0;
  __syncthreads();
  int i = blockIdx.x * 256 + threadIdx.x;
  atomicAdd(&h[rid[i]], 1);
  __syncthreads();
  if (threadIdx.x < NROLE) blkCnt[blockIdx.x * NROLE + threadIdx.x] = h[threadIdx.x];
}

__global__ __launch_bounds__(256) void role_scan(
    const int* __restrict__ blkCnt, int* __restrict__ blkBase,
    int* __restrict__ baseArr, int* __restrict__ cntArr)
{
  __shared__ int c[128 * NROLE];
  __shared__ int bb[128 * NROLE];
  __shared__ int sbase[NROLE], scnt[NROLE];
  for (int i = threadIdx.x; i < 128 * NROLE; i += 256) c[i] = blkCnt[i];
  __syncthreads();
  if (threadIdx.x < NROLE) {
    int k = threadIdx.x, run = 0;
    for (int b = 0; b < 128; ++b) { bb[b * NROLE + k] = run; run += c[b * NROLE + k]; }
    scnt[k] = run;
  }
  __syncthreads();
  if (threadIdx.x == 0) {
    int r = 0;
    for (int k = 0; k < NROLE; ++k) { sbase[k] = r; r += scnt[k]; }
  }
  __syncthreads();
  if (threadIdx.x < NROLE) { baseArr[threadIdx.x] = sbase[threadIdx.x]; cntArr[threadIdx.x] = scnt[threadIdx.x]; }
  for (int i = threadIdx.x; i < 128 * NROLE; i += 256)
    blkBase[i] = bb[i] + sbase[i % NROLE];
}

__global__ __launch_bounds__(256) void role_fill(
    const int* __restrict__ rid, const int* __restrict__ blkBase, int* __restrict__ bucket)
{
  __shared__ int h[NROLE];
  if (threadIdx.x < NROLE) h[threadIdx.x] = 0;
  __syncthreads();
  int i = blockIdx.x * 256 + threadIdx.x;
  int k = rid[i];
  int pos = atomicAdd(&h[k], 1);
  bucket[blkBase[blockIdx.x * NROLE + k] + pos] = i;
}

// ---------------------------------------------------------------- MFMA GEMM
// C[M x N] = relu(A @ Bt^T + bias) [+ gather(E)], bf16 A/Bt/C/E, f32 bias+accum.
// BM=256, BK=64, 512 threads (8 waves, 4 row-waves x 2 col-waves, 64x64 each).
// LDS tiles XOR-swizzled in 16B chunks (chunk ^= row&7) to kill bank conflicts;
// swizzle applied on the *source* address (global_load_lds dst is fixed).
enum { GM_DENSE = 0, GM_GATHER = 1, GM_CONTIG = 2, GM_GATHER_ADD = 3 };

template <int BN, int MODE>
__global__ __launch_bounds__(512, 4) void gemm_bf16(
    const u16* __restrict__ A, const u16* __restrict__ Bt,
    const float* __restrict__ bias, u16* __restrict__ C,
    const u16* __restrict__ E,
    const int* __restrict__ bucket, const int* __restrict__ baseArr,
    const int* __restrict__ cntArr, int M, int N, int K, int ldc)
{
  constexpr int BM = 256, BK = 64;
  constexpr int NF = BN / 32;              // col-frags per wave
  constexpr int BR = BN / 64;              // B staging rounds
  __shared__ __align__(16) u16 As[BM * BK];
  __shared__ __align__(16) u16 Bs[BN * BK];
  const int tid = threadIdx.x;
  const int role = blockIdx.z;
  const int rowBase = blockIdx.x * BM;
  int limit;
  if constexpr (MODE == GM_DENSE) limit = M; else limit = cntArr[role];
  if (rowBase >= limit) return;
  int roleBase = 0;
  if constexpr (MODE != GM_DENSE) roleBase = baseArr[role];
  const u16* BtK = Bt + (size_t)role * N * K + (size_t)blockIdx.y * BN * K;
  const float* biasK = bias + (size_t)role * N + (size_t)blockIdx.y * BN;

  const int lane = tid & 63;
  const int wave = tid >> 6;

  // source chunk swizzle: lane covers (row = r*64 + tid>>3, chunk = tid&7);
  // fetch global chunk (tid&7)^(row&7) so LDS chunk c holds global chunk c^(row&7)
  const int swcol = (((tid & 7) ^ ((tid >> 3) & 7)) * 8);

  u32 aOff[4];                             // element offsets into A
#pragma unroll
  for (int r = 0; r < 4; ++r) {
    int arow = r * 64 + (tid >> 3);
    int i = rowBase + arow;
    if (i >= limit) i = rowBase;           // clamp to a valid row
    int grow;
    if constexpr (MODE == GM_DENSE)       grow = i;
    else if constexpr (MODE == GM_GATHER) grow = bucket[roleBase + i];
    else                                  grow = roleBase + i;   // CONTIG / GATHER_ADD
    aOff[r] = (u32)grow * (u32)K + (u32)swcol;
  }
  u32 bOff[BR];
#pragma unroll
  for (int r = 0; r < BR; ++r)
    bOff[r] = (u32)(r * 64 + (tid >> 3)) * (u32)K + (u32)swcol;

  f32x4 acc[4][NF] = {};

  const int wm = (wave >> 1) * 64;
  const int wn = (wave & 1) * (NF * 16);
  const int quad = lane >> 4;
  const int lm = lane & 15;
  const int l7 = lm & 7;

  for (int k0 = 0; k0 < K; k0 += BK) {
#pragma unroll
    for (int r = 0; r < 4; ++r)
      __builtin_amdgcn_global_load_lds(
          (const __attribute__((address_space(1))) void*)(uintptr_t)(A + aOff[r] + k0),
          (__attribute__((address_space(3))) void*)(&As[r * 4096 + wave * 512]),
          16, 0, 0);
#pragma unroll
    for (int r = 0; r < BR; ++r)
      __builtin_amdgcn_global_load_lds(
          (const __attribute__((address_space(1))) void*)(uintptr_t)(BtK + bOff[r] + k0),
          (__attribute__((address_space(3))) void*)(&Bs[r * 4096 + wave * 512]),
          16, 0, 0);
    __syncthreads();
#pragma unroll
    for (int kk = 0; kk < BK; kk += 32) {
      const int kc = kk >> 3;              // 0 or 4
      bf16x8 af[4], bfr[NF];
#pragma unroll
      for (int i2 = 0; i2 < 4; ++i2) {
        int ar = wm + i2 * 16 + lm;
        af[i2] = *(const bf16x8*)&As[ar * 64 + (((quad + kc) ^ l7) * 8)];
      }
#pragma unroll
      for (int j = 0; j < NF; ++j) {
        int br = wn + j * 16 + lm;
        bfr[j] = *(const bf16x8*)&Bs[br * 64 + (((quad + kc) ^ l7) * 8)];
      }
#pragma unroll
      for (int i2 = 0; i2 < 4; ++i2)
#pragma unroll
        for (int j = 0; j < NF; ++j)
          acc[i2][j] = __builtin_amdgcn_mfma_f32_16x16x32_bf16(af[i2], bfr[j], acc[i2][j], 0, 0, 0);
    }
    __syncthreads();
  }

  // epilogue: C/D layout row=(lane>>4)*4+reg, col=lane&15
#pragma unroll
  for (int i2 = 0; i2 < 4; ++i2) {
#pragma unroll
    for (int r2 = 0; r2 < 4; ++r2) {
      int lrow = wm + i2 * 16 + quad * 4 + r2;
      int i = rowBase + lrow;
      if (i >= limit) continue;
      size_t crow, erow = 0;
      if constexpr (MODE == GM_DENSE) crow = (size_t)i;
      else                            crow = (size_t)(roleBase + i);
      if constexpr (MODE == GM_GATHER_ADD) erow = (size_t)bucket[roleBase + i];
#pragma unroll
      for (int j = 0; j < NF; ++j) {
        int lcol = wn + j * 16 + lm;
        float v = fmaxf(acc[i2][j][r2] + biasK[lcol], 0.f);
        size_t col = (size_t)blockIdx.y * BN + lcol;
        if constexpr (MODE == GM_GATHER_ADD) v += b2f(E[erow * (size_t)ldc + col]);
        C[crow * (size_t)ldc + col] = f2b(v);
      }
    }
  }
}

// ---------------------------------------------------------------- head tail
// per bucket-position p: h1 = relu(h0 @ Wh1[k] + bh1), logits = h1 @ Wh2[k] + bh2, mask
__global__ __launch_bounds__(256) void head_tail(
    const u16* __restrict__ h0buf, const int* __restrict__ bucket,
    const int* __restrict__ baseArr,
    const float* __restrict__ Wh1, const float* __restrict__ bh1,
    const float* __restrict__ Wh2, const float* __restrict__ bh2,
    const float* __restrict__ avail, float* __restrict__ outLogits)
{
  int lane = threadIdx.x & 63;
  int p = blockIdx.x * 4 + (threadIdx.x >> 6);
  int row = bucket[p];
  int k = 0;
#pragma unroll
  for (int j = 1; j < NROLE; ++j) k += (p >= baseArr[j]);
  float h0 = b2f(h0buf[(size_t)p * 64 + lane]);
  int n = lane & 31, half = lane >> 5;
  const float* W1k = Wh1 + k * 64 * 32;
  float a1 = 0.f;
#pragma unroll
  for (int jj = 0; jj < 32; ++jj) {
    int j = half * 32 + jj;
    float hj = __shfl(h0, j, 64);
    a1 += hj * W1k[j * 32 + n];
  }
  a1 += __shfl_xor(a1, 32, 64);
  float h1 = fmaxf(a1 + bh1[k * 32 + n], 0.f);
  const float* W2k = Wh2 + k * 32 * 32;
  float a2 = 0.f;
#pragma unroll
  for (int nn = 0; nn < 32; ++nn) {
    float hn = __shfl(h1, nn, 64);   // lane nn holds h1[nn]
    a2 += hn * W2k[nn * 32 + n];
  }
  float logit = a2 + bh2[k * 32 + n];
  float av = avail[(size_t)row * 32 + n];
  if (av <= 0.5f) logit = -1e10f;
  if (half == 0) outLogits[(size_t)row * 32 + n] = logit;
}

// ---------------------------------------------------------------- launcher
extern "C" void kernel_launch(void* const* d_in, const int* in_sizes, int n_in,
                              void* d_out, int out_size, void* d_ws, size_t ws_size,
                              hipStream_t stream)
{
  const float* rnn  = (const float*)d_in[0];
  const float* obs  = (const float*)d_in[1];
  const float* avail= (const float*)d_in[3];
  const int*   rid  = (const int*)d_in[4];
  const float* fn_s = (const float*)d_in[5];
  const float* fn_b = (const float*)d_in[6];
  const float* W0   = (const float*)d_in[7];
  const float* b0   = (const float*)d_in[8];
  const float* ln0s = (const float*)d_in[9];
  const float* ln0b = (const float*)d_in[10];
  const float* W1   = (const float*)d_in[11];
  const float* b1   = (const float*)d_in[12];
  const float* ln1s = (const float*)d_in[13];
  const float* ln1b = (const float*)d_in[14];
  const float* Wr0  = (const float*)d_in[15];
  const float* br0  = (const float*)d_in[16];
  const float* Wr1  = (const float*)d_in[17];
  const float* br1  = (const float*)d_in[18];
  const float* Wh0  = (const float*)d_in[19];
  const float* bh0  = (const float*)d_in[20];
  const float* Wh1  = (const float*)d_in[21];
  const float* bh1  = (const float*)d_in[22];
  const float* Wh2  = (const float*)d_in[23];
  const float* bh2  = (const float*)d_in[24];

  const int ROWS = 32768;           // T*B

  char* w = (char*)d_ws;
  auto carve = [&](size_t bytes) { char* p = w; w += (bytes + 255) & ~(size_t)255; return p; };
  u16* obs_n  = (u16*)carve((size_t)ROWS * 256 * 2);
  u16* bufA   = (u16*)carve((size_t)ROWS * 512 * 2);   // reused: gemm out, then e_bucket
  u16* bufB   = (u16*)carve((size_t)ROWS * 512 * 2);   // LN outputs (e)
  u16* r_buf  = (u16*)carve((size_t)ROWS * 128 * 2);
  u16* h0buf  = (u16*)carve((size_t)ROWS * 64 * 2);
  u16* W0t    = (u16*)carve((size_t)512 * 256 * 2);
  u16* W1t    = (u16*)carve((size_t)512 * 512 * 2);
  u16* Wr0t   = (u16*)carve((size_t)6 * 128 * 256 * 2);
  u16* Wr1t   = (u16*)carve((size_t)6 * 512 * 128 * 2);
  u16* Wh0t   = (u16*)carve((size_t)6 * 64 * 512 * 2);
  int* bucket = (int*)carve((size_t)ROWS * 4);
  int* blkCnt = (int*)carve((size_t)128 * NROLE * 4);
  int* blkBase= (int*)carve((size_t)128 * NROLE * 4);
  int* baseArr= (int*)carve(256);
  int* cntArr = (int*)carve(256);

  float* outLogits = (float*)d_out + (size_t)1024 * 512;   // after rnn passthrough

  // rnn_states passthrough (f32)
  hipMemcpyAsync(d_out, rnn, (size_t)1024 * 512 * 4, hipMemcpyDeviceToDevice, stream);

  // all weight convert+transposes, one launch
  transpose_all<<<1152, 256, 0, stream>>>(W0, W1, Wr0, Wr1, Wh0, W0t, W1t, Wr0t, Wr1t, Wh0t);

  // feature norm (f32 obs -> bf16 obs_n)
  ln_f32_256<<<8192, 256, 0, stream>>>(obs, fn_s, fn_b, obs_n, ROWS);

  // role bucketing
  role_count<<<128, 256, 0, stream>>>(rid, blkCnt);
  role_scan<<<1, 256, 0, stream>>>(blkCnt, blkBase, baseArr, cntArr);
  role_fill<<<128, 256, 0, stream>>>(rid, blkBase, bucket);

  // base MLP
  gemm_bf16<128, GM_DENSE><<<dim3(128, 4, 1), 512, 0, stream>>>(
      obs_n, W0t, b0, bufA, nullptr, nullptr, nullptr, nullptr, ROWS, 512, 256, 512);
  ln_bf16_512<<<8192, 256, 0, stream>>>(bufA, ln0s, ln0b, bufB, ROWS);
  gemm_bf16<128, GM_DENSE><<<dim3(128, 4, 1), 512, 0, stream>>>(
      bufB, W1t, b1, bufA, nullptr, nullptr, nullptr, nullptr, ROWS, 512, 512, 512);
  ln_bf16_512<<<8192, 256, 0, stream>>>(bufA, ln1s, ln1b, bufB, ROWS);   // bufB = e

  // role routes: r1 = relu(obs_n[bucket] @ Wr0) (bucket-ordered, contiguous)
  gemm_bf16<128, GM_GATHER><<<dim3(128, 1, 6), 512, 0, stream>>>(
      obs_n, Wr0t, br0, r_buf, nullptr, bucket, baseArr, cntArr, ROWS, 128, 256, 128);
  // e_bucket[p] = e[bucket[p]] + relu(r1 @ Wr1) -> bufA (contiguous, bucket-ordered)
  gemm_bf16<128, GM_GATHER_ADD><<<dim3(128, 4, 6), 512, 0, stream>>>(
      r_buf, Wr1t, br1, bufA, bufB, bucket, baseArr, cntArr, ROWS, 512, 128, 512);

  // head first layer: e_bucket -> 64 (all-contiguous)
  gemm_bf16<64, GM_CONTIG><<<dim3(128, 1, 6), 512, 0, stream>>>(
      bufA, Wh0t, bh0, h0buf, nullptr, bucket, baseArr, cntArr, ROWS, 64, 512, 64);

  // head tail: 64 -> 32 -> 32 + mask (f32 out, scatter by bucket)
  head_tail<<<8192, 256, 0, stream>>>(h0buf, bucket, baseArr, Wh1, bh1, Wh2, bh2, avail, outLogits);
}